// Round 6
// baseline (169.562 us; speedup 1.0000x reference)
//
#include <hip/hip_runtime.h>
#include <math.h>

typedef __bf16 bf16_t;
typedef bf16_t bf16x8 __attribute__((ext_vector_type(8)));
typedef float  f32x16 __attribute__((ext_vector_type(16)));
typedef float  f32x4  __attribute__((ext_vector_type(4)));

#define MFMA32(a, b, c) __builtin_amdgcn_mfma_f32_32x32x16_bf16((a), (b), (c), 0, 0, 0)

static __device__ __forceinline__ unsigned pk_bf16(float a, float b) {
  union { bf16_t h[2]; unsigned u; } t;
  t.h[0] = (bf16_t)a;
  t.h[1] = (bf16_t)b;
  return t.u;
}

// 1-bit sign-smear: returns 0x00000000 or 0xFFFFFFFF from bit `pos` of w.
static __device__ __forceinline__ int bit_smear(unsigned w, int pos) {
#if __has_builtin(__builtin_amdgcn_sbfe)
  return __builtin_amdgcn_sbfe((int)w, pos, 1);
#else
  return ((int)(w << (31 - pos))) >> 31;
#endif
}

// ---------------- prepass3: K frag | V frag | inverted permuted mask bits ----
// (unchanged — layouts proven R2/R3)
__global__ __launch_bounds__(256) void prepass3(
    const float* __restrict__ kp, const float* __restrict__ vp,
    const int* __restrict__ maskp, bf16_t* __restrict__ kfr,
    bf16_t* __restrict__ vfr, unsigned* __restrict__ mq) {
  const int bx  = blockIdx.x;
  const int tid = threadIdx.x;

  if (bx < 2048) {
    const size_t t = (size_t)bx * 256 + tid;
    const int ln = t & 63, dc = (t >> 6) & 3;
    const int kh = (t >> 8) & 63, bh = (int)(t >> 14);
    const float* s = kp + ((size_t)(bh * 2048 + kh * 32 + (ln & 31))) * 64 +
                     dc * 16 + (ln >> 5) * 8;
    f32x4 a0 = *(const f32x4*)s;
    f32x4 a1 = *(const f32x4*)(s + 4);
    bf16x8 w;
#pragma unroll
    for (int j = 0; j < 4; ++j) { w[j] = (bf16_t)a0[j]; w[4 + j] = (bf16_t)a1[j]; }
    *(bf16x8*)(kfr + t * 8) = w;
  } else if (bx < 4096) {
    const size_t t = (size_t)(bx - 2048) * 256 + tid;
    const int ln = t & 63, rr = (t >> 6) & 1, kc = (t >> 7) & 1;
    const int p = (t >> 8) & 1, kt = (t >> 9) & 31, bh = (int)(t >> 14);
    const int d    = rr * 32 + (ln & 31);
    const int hh   = ln >> 5;
    const int kb   = kt * 64 + p * 32 + kc * 16;
    const float* s = vp + ((size_t)(bh * 2048 + kb)) * 64 + d;
    bf16_t w[8];
#pragma unroll
    for (int j = 0; j < 8; ++j) {
      const int key = hh * 4 + (j & 3) + 8 * (j >> 2);
      w[j] = (bf16_t)fminf(s[(size_t)key * 64], 0.f);
    }
    *(bf16x8*)(vfr + t * 8) = *(bf16x8*)w;
  } else {
    const unsigned gt = (unsigned)(bx - 4096) * 256u + (unsigned)tid;
    const int q  = gt & 2047;
    const int p  = (gt >> 11) & 1;
    const int it = (gt >> 12) & 31;
    const int b  = (int)(gt >> 17);
    const int* mr = maskp + ((size_t)b * 2048 + q) * 2048 + it * 64 + p * 32;
    int m[32];
#pragma unroll
    for (int i = 0; i < 8; ++i) {
      const int4 a = *(const int4*)(mr + i * 4);
      m[i * 4 + 0] = a.x; m[i * 4 + 1] = a.y;
      m[i * 4 + 2] = a.z; m[i * 4 + 3] = a.w;
    }
    unsigned w = 0;
#pragma unroll
    for (int j = 0; j < 32; ++j) {
      const int koff = (j & 3) + 8 * ((j >> 2) & 3) + 4 * (j >> 4);
      if (m[koff] == 0) w |= (1u << j);
    }
    mq[((size_t)(b * 32 + it) * 2 + p) * 2048 + q] = w;
  }
}

// ---------------- main kernel v7: R3 structure, CORRECT register bound ------
// Session diagnosis: all 64-q kernels are grid-limited (1024 blocks = exactly
// 4 blocks/CU); both pipes <52% busy, ~40% of cycles are unhidden dependency
// stalls. This is R3's ws4 (32-q tiles, grid 2048, 4-way key split per iter,
// LDS 18.4 KB, numerics PASSED in R3) with the ONE fix: launch_bounds
// (256,8)->(256,4). R3's failure was purely the forced 64-reg cap (total
// spill: 693 MB scratch). Live set ~96 total (64 arch + 32 acc, measured on
// every sibling) -> no spill at cap 128, and 96 regs/wave admits 5 waves/SIMD
// = 20 waves/CU (reg-limited), vs 16 grid-limited today. Grid 2048 + LDS
// 18.4 KB (8 blocks/CU possible) supply the extra blocks.
__global__ __launch_bounds__(256, 4) void nrev_attn_ws7(
    const float* __restrict__ qp, const bf16_t* __restrict__ kfr,
    const bf16_t* __restrict__ vfr, const unsigned* __restrict__ mq,
    float* __restrict__ outp) {
  constexpr int L = 2048, D = 64;
  __shared__ float Oe[2][32][68];
  __shared__ float lsum[4][2][32];  // [wave][hh][col]

  const int tid  = threadIdx.x;
  const int lane = tid & 63;
  const int wv   = tid >> 6;
  const int col  = lane & 31;
  const int hh   = lane >> 5;
  const int hsh  = hh << 4;
  const int blk  = blockIdx.x;
  const int bh   = (blk & 7) * 4 + (blk >> 9);   // XCD swizzle: XCD x owns bh [4x,4x+4)
  const int qt   = (blk >> 3) & 63;
  const int bb   = bh >> 4;
  const int q0   = qt * 32;
  const float c1 = 0.18033688011112042f;  // 0.125 * log2(e), folded into Q

  // Q fragments (B-operand of S^T = K*Q^T). Same 32-q fragment for all waves.
  bf16x8 qf[4];
  {
    const float* gq = qp + (size_t)(bh * L + q0 + col) * D;
#pragma unroll
    for (int dc = 0; dc < 4; ++dc) {
      const float* ptr = gq + dc * 16 + hh * 8;
      f32x4 f0 = *(const f32x4*)ptr;
      f32x4 f1 = *(const f32x4*)(ptr + 4);
      bf16x8 t;
#pragma unroll
      for (int j = 0; j < 4; ++j) {
        t[j]     = (bf16_t)(f0[j] * c1);
        t[4 + j] = (bf16_t)(f1[j] * c1);
      }
      qf[dc] = t;
    }
  }

  // Wave (w2,p) handles keys (4*it + 2*w2 + p)*32 .. +32 each iter.
  const int w2 = wv >> 1;
  const int p  = wv & 1;
  const char* kpt = (const char*)kfr + (size_t)bh * 262144 + w2 * 8192 +
                    p * 4096 + (size_t)lane * 16;
  const char* vpt = (const char*)vfr + (size_t)bh * 262144 + w2 * 8192 +
                    p * 4096 + (size_t)lane * 16;
  const int qq = q0 + col;
  const unsigned* mpt = mq + ((size_t)(bb * 32 + w2) * 2 + p) * 2048 + qq;

  f32x16 acc0, acc1;
#pragma unroll
  for (int i = 0; i < 16; ++i) { acc0[i] = 0.f; acc1[i] = 0.f; }
  float l_run = 0.f;

  bf16x8 kf0 = *(const bf16x8*)(kpt + 0);
  bf16x8 kf1 = *(const bf16x8*)(kpt + 1024);
  bf16x8 kf2 = *(const bf16x8*)(kpt + 2048);
  bf16x8 kf3 = *(const bf16x8*)(kpt + 3072);
  unsigned bitsw = mpt[0];

  for (int it = 0; it < 16; ++it) {
    const int itn = (it < 15) ? it + 1 : 15;  // clamped; value unused last iter
    const char* kn = kpt + (size_t)itn * 16384;
    bf16x8 kn0 = *(const bf16x8*)(kn + 0);
    bf16x8 kn1 = *(const bf16x8*)(kn + 1024);
    bf16x8 kn2 = *(const bf16x8*)(kn + 2048);
    bf16x8 kn3 = *(const bf16x8*)(kn + 3072);
    const unsigned bw_n = mpt[(size_t)itn * 8192];
    const char* vg = vpt + (size_t)it * 16384;
    bf16x8 vf0 = *(const bf16x8*)(vg + 0);     // kc0, d 0-31
    bf16x8 vf1 = *(const bf16x8*)(vg + 1024);  // kc0, d 32-63
    bf16x8 vf2 = *(const bf16x8*)(vg + 2048);  // kc1, d 0-31
    bf16x8 vf3 = *(const bf16x8*)(vg + 3072);  // kc1, d 32-63

    // Bias-init: element r gets 0.0 (visible) or -16384.0 (masked);
    // exp2(s-16384) underflows to exact 0.
    const unsigned wsh = bitsw >> hsh;
    f32x16 st0;
#pragma unroll
    for (int r = 0; r < 16; ++r)
      st0[r] = __uint_as_float((unsigned)bit_smear(wsh, r) & 0xC6800000u);

    // S^T = K_tile * Q^T (32 keys x 32 q), K-dim 64 via 4 chained MFMAs.
    st0 = MFMA32(kf0, qf[0], st0);
    st0 = MFMA32(kf1, qf[1], st0);
    st0 = MFMA32(kf2, qf[2], st0);
    st0 = MFMA32(kf3, qf[3], st0);

#pragma unroll
    for (int r = 0; r < 16; ++r) st0[r] = __builtin_amdgcn_exp2f(st0[r]);

    // Denominator: 15-op VALU tree (short chain, cheap issue).
    {
      const float t0 = (st0[0] + st0[1]) + (st0[2] + st0[3]);
      const float t1 = (st0[4] + st0[5]) + (st0[6] + st0[7]);
      const float t2 = (st0[8] + st0[9]) + (st0[10] + st0[11]);
      const float t3 = (st0[12] + st0[13]) + (st0[14] + st0[15]);
      l_run += (t0 + t1) + (t2 + t3);
    }

    // Pack RNE; PV MFMAs (natural P lane order, V' permuted at prepass).
    union { unsigned u[4]; bf16x8 v; } b0;
    b0.u[0] = pk_bf16(st0[0], st0[1]);
    b0.u[1] = pk_bf16(st0[2], st0[3]);
    b0.u[2] = pk_bf16(st0[4], st0[5]);
    b0.u[3] = pk_bf16(st0[6], st0[7]);
    acc0 = MFMA32(vf0, b0.v, acc0);
    acc1 = MFMA32(vf1, b0.v, acc1);

    union { unsigned u[4]; bf16x8 v; } b1;
    b1.u[0] = pk_bf16(st0[8],  st0[9]);
    b1.u[1] = pk_bf16(st0[10], st0[11]);
    b1.u[2] = pk_bf16(st0[12], st0[13]);
    b1.u[3] = pk_bf16(st0[14], st0[15]);
    acc0 = MFMA32(vf2, b1.v, acc0);
    acc1 = MFMA32(vf3, b1.v, acc1);

    kf0 = kn0; kf1 = kn1; kf2 = kn2; kf3 = kn3;
    bitsw = bw_n;
  }

  // ---- epilogue: merge 4 waves' partial l and O ----
  lsum[wv][hh][col] = l_run;
  __syncthreads();
  float ls = 0.f;
#pragma unroll
  for (int w = 0; w < 4; ++w) ls += lsum[w][0][col] + lsum[w][1][col];
  const float scale = 1.f / ls;

  if (wv < 2) {
#pragma unroll
    for (int dt = 0; dt < 2; ++dt)
#pragma unroll
      for (int g2 = 0; g2 < 4; ++g2) {
        f32x4 w;
#pragma unroll
        for (int j = 0; j < 4; ++j)
          w[j] = (dt ? acc1[g2 * 4 + j] : acc0[g2 * 4 + j]) * scale;
        *(f32x4*)&Oe[wv][col][g2 * 8 + hh * 4 + dt * 32] = w;
      }
  }
  __syncthreads();
  if (wv >= 2) {
#pragma unroll
    for (int dt = 0; dt < 2; ++dt)
#pragma unroll
      for (int g2 = 0; g2 < 4; ++g2) {
        float* dst = &Oe[wv - 2][col][g2 * 8 + hh * 4 + dt * 32];
        f32x4 w = *(f32x4*)dst;
#pragma unroll
        for (int j = 0; j < 4; ++j)
          w[j] += (dt ? acc1[g2 * 4 + j] : acc0[g2 * 4 + j]) * scale;
        *(f32x4*)dst = w;
      }
  }
  __syncthreads();
#pragma unroll
  for (int i = 0; i < 2; ++i) {
    const int idx = tid + i * 256;
    const int row = idx >> 4, c4 = idx & 15;
    f32x4 v0 = *(const f32x4*)&Oe[0][row][c4 * 4];
    f32x4 v1 = *(const f32x4*)&Oe[1][row][c4 * 4];
    f32x4 vs = v0 + v1;
    *(f32x4*)&outp[(size_t)(bh * L + q0 + row) * D + c4 * 4] = vs;
  }
}

// ---------------- fallback (no workspace): proven R2/R3 kernel ----------------
__global__ __launch_bounds__(256, 4) void nrev_attn_fb(
    const float* __restrict__ qp, const float* __restrict__ kp,
    const float* __restrict__ vp, const int* __restrict__ maskp,
    float* __restrict__ outp) {
  constexpr int L = 2048, D = 64;
  __shared__ union alignas(16) SMem {
    struct {
      bf16_t K[64 * 72];
      bf16_t V[64 * 72];
      unsigned long long mb[64];
    } s;
    float Oe[2][64][68];
  } sm;
  __shared__ float mlbuf[2][2][32][2];

  const int tid  = threadIdx.x;
  const int lane = tid & 63;
  const int wv   = tid >> 6;
  const int p    = wv >> 1;
  const int g    = wv & 1;
  const int col  = lane & 31;
  const int hh   = lane >> 5;
  const int blk  = blockIdx.x;
  const int bh   = (blk & 7) * 4 + (blk >> 8);
  const int qt   = (blk >> 3) & 31;
  const int bb   = bh >> 4;
  const int q0   = qt * 64;
  const float c1 = 0.18033688011112042f;

  bf16x8 qf[4];
  {
    const float* gq = qp + (size_t)(bh * L + q0 + g * 32 + col) * D;
#pragma unroll
    for (int dc = 0; dc < 4; ++dc) {
      const float* ptr = gq + dc * 16 + hh * 8;
      f32x4 f0 = *(const f32x4*)ptr;
      f32x4 f1 = *(const f32x4*)(ptr + 4);
      bf16x8 t;
#pragma unroll
      for (int j = 0; j < 4; ++j) {
        t[j]     = (bf16_t)(f0[j] * c1);
        t[4 + j] = (bf16_t)(f1[j] * c1);
      }
      qf[dc] = t;
    }
  }

  f32x16 acc0, acc1;
#pragma unroll
  for (int i = 0; i < 16; ++i) { acc0[i] = 0.f; acc1[i] = 0.f; }
  float m_run = -__builtin_inff();
  float l_run = 0.f;

  for (int kt = 0; kt < L; kt += 64) {
    __syncthreads();
    {
      const int key = tid >> 2, dp = tid & 3;
      const float* gk = kp + (size_t)(bh * L + kt + key) * D + dp * 16;
      f32x4 a0 = *(const f32x4*)gk;
      f32x4 a1 = *(const f32x4*)(gk + 4);
      f32x4 a2 = *(const f32x4*)(gk + 8);
      f32x4 a3 = *(const f32x4*)(gk + 12);
      bf16x8 w0, w1;
#pragma unroll
      for (int j = 0; j < 4; ++j) {
        w0[j] = (bf16_t)a0[j]; w0[4 + j] = (bf16_t)a1[j];
        w1[j] = (bf16_t)a2[j]; w1[4 + j] = (bf16_t)a3[j];
      }
      *(bf16x8*)&sm.s.K[key * 72 + dp * 16]     = w0;
      *(bf16x8*)&sm.s.K[key * 72 + dp * 16 + 8] = w1;
    }
    {
      const int w16 = wv * 16;
      const float* gv = vp + (size_t)(bh * L + kt + w16) * D + lane;
      bf16x8 w0, w1;
#pragma unroll
      for (int i = 0; i < 8; ++i) {
        w0[i] = (bf16_t)fminf(gv[(size_t)i * D], 0.f);
        w1[i] = (bf16_t)fminf(gv[(size_t)(i + 8) * D], 0.f);
      }
      *(bf16x8*)&sm.s.V[lane * 72 + w16]     = w0;
      *(bf16x8*)&sm.s.V[lane * 72 + w16 + 8] = w1;
    }
    for (int i = 0; i < 16; ++i) {
      const int row = wv * 16 + i;
      int mv = maskp[(size_t)bb * L * L + (size_t)(q0 + row) * L + kt + lane];
      unsigned long long bal = __ballot(mv != 0);
      if (lane == 0) sm.s.mb[row] = bal;
    }
    __syncthreads();

    f32x16 st0;
#pragma unroll
    for (int i = 0; i < 16; ++i) st0[i] = 0.f;
#pragma unroll
    for (int dc = 0; dc < 4; ++dc) {
      bf16x8 a0 = *(const bf16x8*)&sm.s.K[(p * 32 + col) * 72 + dc * 16 + hh * 8];
      st0 = MFMA32(a0, qf[dc], st0);
    }

    float M = st0[0];
#pragma unroll
    for (int r = 1; r < 16; ++r) M = fmaxf(M, st0[r]);
#pragma unroll
    for (int sh = 1; sh < 64; sh <<= 1) M = fmaxf(M, __shfl_xor(M, sh));
    if (M > m_run) {
      const float alpha = exp2f(m_run - M);
      l_run *= alpha;
#pragma unroll
      for (int r = 0; r < 16; ++r) { acc0[r] *= alpha; acc1[r] *= alpha; }
      m_run = M;
    }

    const unsigned long long bits = sm.s.mb[g * 32 + col];
    const unsigned kb = ((unsigned)(bits >> (32 * p))) >> (4 * hh);
    float Sl = 0.f;
#pragma unroll
    for (int r = 0; r < 16; ++r) {
      const int c = (r & 3) + 8 * (r >> 2);
      float p0 = exp2f(st0[r] - m_run);
      p0 = ((kb >> c) & 1u) ? p0 : 0.f;
      st0[r] = p0;
      Sl += p0;
    }
    Sl += __shfl_xor(Sl, 32);
    l_run += Sl;

#pragma unroll
    for (int kc = 0; kc < 2; ++kc) {
      const unsigned pk0  = pk_bf16(st0[8 * kc + 0], st0[8 * kc + 1]);
      const unsigned pk0b = pk_bf16(st0[8 * kc + 2], st0[8 * kc + 3]);
      const unsigned pk1  = pk_bf16(st0[8 * kc + 4], st0[8 * kc + 5]);
      const unsigned pk1b = pk_bf16(st0[8 * kc + 6], st0[8 * kc + 7]);
      const unsigned sh0  = __shfl_xor(pk0, 32);
      const unsigned sh0b = __shfl_xor(pk0b, 32);
      const unsigned sh1  = __shfl_xor(pk1, 32);
      const unsigned sh1b = __shfl_xor(pk1b, 32);
      union { unsigned u[4]; bf16x8 v; } bbv;
      bbv.u[0] = hh ? sh1  : pk0;
      bbv.u[1] = hh ? sh1b : pk0b;
      bbv.u[2] = hh ? pk1  : sh0;
      bbv.u[3] = hh ? pk1b : sh0b;
      const int kbase = p * 32 + kc * 16 + hh * 8;
      bf16x8 av0 = *(const bf16x8*)&sm.s.V[col * 72        + kbase];
      bf16x8 av1 = *(const bf16x8*)&sm.s.V[(col + 32) * 72 + kbase];
      acc0 = MFMA32(av0, bbv.v, acc0);
      acc1 = MFMA32(av1, bbv.v, acc1);
    }
  }

  if (hh == 0) {
    mlbuf[g][p][col][0] = m_run;
    mlbuf[g][p][col][1] = l_run;
  }
  __syncthreads();
  const float m0 = mlbuf[g][0][col][0], l0v = mlbuf[g][0][col][1];
  const float m1 = mlbuf[g][1][col][0], l1v = mlbuf[g][1][col][1];
  const float ms = fmaxf(m0, m1);
  const float a0s = exp2f(m0 - ms), a1s = exp2f(m1 - ms);
  const float lst = a0s * l0v + a1s * l1v;
  const float scale = (p ? a1s : a0s) / lst;

#pragma unroll
  for (int dt = 0; dt < 2; ++dt)
#pragma unroll
    for (int g2 = 0; g2 < 4; ++g2) {
      f32x4 w;
#pragma unroll
      for (int j = 0; j < 4; ++j)
        w[j] = (dt ? acc1[g2 * 4 + j] : acc0[g2 * 4 + j]) * scale;
      *(f32x4*)&sm.Oe[p][g * 32 + col][g2 * 8 + hh * 4 + dt * 32] = w;
    }
  __syncthreads();
#pragma unroll
  for (int i = 0; i < 4; ++i) {
    const int idx = tid + i * 256;
    const int row = idx >> 4, c4 = idx & 15;
    f32x4 v0 = *(const f32x4*)&sm.Oe[0][row][c4 * 4];
    f32x4 v1 = *(const f32x4*)&sm.Oe[1][row][c4 * 4];
    f32x4 vs = v0 + v1;
    *(f32x4*)&outp[(size_t)(bh * L + q0 + row) * D + c4 * 4] = vs;
  }
}

extern "C" void kernel_launch(void* const* d_in, const int* in_sizes, int n_in,
                              void* d_out, int out_size, void* d_ws, size_t ws_size,
                              hipStream_t stream) {
  (void)in_sizes; (void)n_in; (void)out_size;
  const float* qp = (const float*)d_in[0];
  const float* kp = (const float*)d_in[1];
  const float* vp = (const float*)d_in[2];
  const int*   mp = (const int*)d_in[3];
  float* op = (float*)d_out;

  // ws layout: K' frag bf16 8 MiB | V' frag bf16 8 MiB | mask bits 1 MiB
  const size_t kOff = 0;
  const size_t vOff = (size_t)8 * 1024 * 1024;
  const size_t mOff = (size_t)16 * 1024 * 1024;
  const size_t need = mOff + (size_t)1024 * 1024;

  if (d_ws != nullptr && ws_size >= need) {
    bf16_t* kb = (bf16_t*)((char*)d_ws + kOff);
    bf16_t* vt = (bf16_t*)((char*)d_ws + vOff);
    unsigned* mqp = (unsigned*)((char*)d_ws + mOff);
    hipLaunchKernelGGL(prepass3, dim3(5120), dim3(256), 0, stream,
                       kp, vp, mp, kb, vt, mqp);
    hipLaunchKernelGGL(nrev_attn_ws7, dim3(2048), dim3(256), 0, stream,
                       qp, kb, vt, mqp, op);
  } else {
    hipLaunchKernelGGL(nrev_attn_fb, dim3(1024), dim3(256), 0, stream,
                       qp, kp, vp, mp, op);
  }
}

// Round 7
// 162.210 us; speedup vs baseline: 1.0453x; 1.0453x over previous
//
#include <hip/hip_runtime.h>
#include <math.h>

typedef __bf16 bf16_t;
typedef bf16_t bf16x8 __attribute__((ext_vector_type(8)));
typedef float  f32x16 __attribute__((ext_vector_type(16)));
typedef float  f32x4  __attribute__((ext_vector_type(4)));

#define MFMA32(a, b, c) __builtin_amdgcn_mfma_f32_32x32x16_bf16((a), (b), (c), 0, 0, 0)

static __device__ __forceinline__ unsigned pk_bf16(float a, float b) {
  union { bf16_t h[2]; unsigned u; } t;
  t.h[0] = (bf16_t)a;
  t.h[1] = (bf16_t)b;
  return t.u;
}

// Truncating bf16 pair pack: lo16 = a[31:16], hi16 = b[31:16]. 2 VALU ops.
static __device__ __forceinline__ unsigned pk_trunc(float a, float b) {
  return (__float_as_uint(a) >> 16) | (__float_as_uint(b) & 0xFFFF0000u);
}

// ---------------- fused prepass (R0-proven, byte-identical) ----------------
// Sect 0: K fp32 -> K' bf16 QK-A-fragment order.
// Sect 1: V fp32 -> neg-relu bf16 V' PV-A-fragment order with baked key perm.
// Sect 2: mask int32 (B,1,L,L) -> u64 words [b][kw(32)][q(2048)]
__global__ __launch_bounds__(256) void prepass(
    const float* __restrict__ kp, const float* __restrict__ vp,
    const int* __restrict__ maskp, bf16_t* __restrict__ kfr,
    bf16_t* __restrict__ vfr, unsigned long long* __restrict__ mpk) {
  const int sect = blockIdx.x >> 11;
  const int blk  = blockIdx.x & 2047;
  const int tid  = threadIdx.x;

  if (sect == 0) {
    const size_t t = (size_t)blk * 256 + tid;
    const int ln = t & 63, dc = (t >> 6) & 3;
    const int kh = (t >> 8) & 63, bh = (int)(t >> 14);
    const float* s = kp + ((size_t)(bh * 2048 + kh * 32 + (ln & 31))) * 64 +
                     dc * 16 + (ln >> 5) * 8;
    f32x4 a0 = *(const f32x4*)s;
    f32x4 a1 = *(const f32x4*)(s + 4);
    bf16x8 w;
#pragma unroll
    for (int j = 0; j < 4; ++j) { w[j] = (bf16_t)a0[j]; w[4 + j] = (bf16_t)a1[j]; }
    *(bf16x8*)(kfr + t * 8) = w;
  } else if (sect == 1) {
    const size_t t = (size_t)blk * 256 + tid;
    const int ln = t & 63, rr = (t >> 6) & 1, kc = (t >> 7) & 1;
    const int p = (t >> 8) & 1, kt = (t >> 9) & 31, bh = (int)(t >> 14);
    const int d    = rr * 32 + (ln & 31);
    const int hh   = ln >> 5;
    const int kb   = kt * 64 + p * 32 + kc * 16;  // 16-key group base
    const float* s = vp + ((size_t)(bh * 2048 + kb)) * 64 + d;
    bf16_t w[8];
#pragma unroll
    for (int j = 0; j < 8; ++j) {
      const int key = hh * 4 + (j & 3) + 8 * (j >> 2);  // perm
      w[j] = (bf16_t)fminf(s[(size_t)key * 64], 0.f);
    }
    *(bf16x8*)(vfr + t * 8) = *(bf16x8*)w;
  } else {
    const int lane = tid & 63;
    const int gw   = blk * 4 + (tid >> 6);
    const int bq   = gw >> 1, half = gw & 1;
    const int b    = bq >> 11, q = bq & 2047;
    const size_t base = (size_t)bq * 2048 + half * 1024;
    unsigned long long w = 0;
#pragma unroll
    for (int j = 0; j < 16; ++j) {
      const int mv = maskp[base + j * 64 + lane];
      const unsigned long long bal = __ballot(mv != 0);
      if (lane == j) w = bal;
    }
    if (lane < 16) mpk[((size_t)b * 32 + half * 16 + lane) * 2048 + q] = w;
  }
}

// ---------------- main kernel v8: exact R0 body + s_setprio on MFMA clusters -
// Seven rounds of data: R0's barrier-free 64-q schedule (56.5 us) beats every
// restructure (VALU cuts, bias-init, pipelining, occupancy tiles) by 3-9 us.
// Neither pipe saturated (VALU 52%, MFMA 25%) -> latency floor of the chain.
// One untried, regime-matched knob remains: s_setprio(1) around the MFMA
// clusters (T5). R0's K-loop has NO barriers, so the 4 waves/SIMD drift to
// different phases — exactly the attn regime where setprio measured +4-7%
// (null only on barrier-lockstep GEMM). Everything else byte-identical to R0.
__global__ __launch_bounds__(256, 4) void nrev_attn_ws8(
    const float* __restrict__ qp, const bf16_t* __restrict__ kfr,
    const bf16_t* __restrict__ vfr, const unsigned long long* __restrict__ mpk,
    float* __restrict__ outp) {
  constexpr int L = 2048, D = 64;
  __shared__ float Oe[2][64][68];
  __shared__ float lsum[2][2][2][32];   // [g][p][hh][col]

  const int tid  = threadIdx.x;
  const int lane = tid & 63;
  const int wv   = tid >> 6;
  const int p    = wv >> 1;
  const int g    = wv & 1;
  const int col  = lane & 31;
  const int hh   = lane >> 5;
  const int blk  = blockIdx.x;
  const int bh   = (blk & 7) * 4 + (blk >> 8);   // XCD swizzle (R2: FETCH 5x cut)
  const int qt   = (blk >> 3) & 31;
  const int bb   = bh >> 4;
  const int q0   = qt * 64;
  const float c1 = 0.18033688011112042f;  // 0.125 * log2(e), folded into Q

  // Q fragments (B-operand of S^T = K*Q^T).
  bf16x8 qf[4];
  {
    const float* gq = qp + (size_t)(bh * L + q0 + g * 32 + col) * D;
#pragma unroll
    for (int dc = 0; dc < 4; ++dc) {
      const float* ptr = gq + dc * 16 + hh * 8;
      f32x4 f0 = *(const f32x4*)ptr;
      f32x4 f1 = *(const f32x4*)(ptr + 4);
      bf16x8 t;
#pragma unroll
      for (int j = 0; j < 4; ++j) {
        t[j]     = (bf16_t)(f0[j] * c1);
        t[4 + j] = (bf16_t)(f1[j] * c1);
      }
      qf[dc] = t;
    }
  }

  const char* kpt = (const char*)kfr + (size_t)bh * 262144 + p * 4096 + (size_t)lane * 16;
  const char* vpt = (const char*)vfr + (size_t)bh * 262144 + p * 4096 + (size_t)lane * 16;
  const unsigned long long* mrow = mpk + (size_t)bb * 65536 + q0 + g * 32 + col;

  f32x16 acc0, acc1;
#pragma unroll
  for (int i = 0; i < 16; ++i) { acc0[i] = 0.f; acc1[i] = 0.f; }
  float l_run = 0.f;  // partial over own (p,hh) keys only; merged in epilogue

  bf16x8 kf0 = *(const bf16x8*)(kpt + 0);
  bf16x8 kf1 = *(const bf16x8*)(kpt + 1024);
  bf16x8 kf2 = *(const bf16x8*)(kpt + 2048);
  bf16x8 kf3 = *(const bf16x8*)(kpt + 3072);
  unsigned long long bits = mrow[0];

  for (int it = 0; it < 32; ++it) {
    const int itn = (it < 31) ? it + 1 : 31;  // clamped; value unused last iter
    const char* kn = kpt + (size_t)itn * 8192;
    bf16x8 kn0 = *(const bf16x8*)(kn + 0);
    bf16x8 kn1 = *(const bf16x8*)(kn + 1024);
    bf16x8 kn2 = *(const bf16x8*)(kn + 2048);
    bf16x8 kn3 = *(const bf16x8*)(kn + 3072);
    const char* vg = vpt + (size_t)it * 8192;
    bf16x8 vf0 = *(const bf16x8*)(vg + 0);     // kc0, d 0-31
    bf16x8 vf1 = *(const bf16x8*)(vg + 1024);  // kc0, d 32-63
    bf16x8 vf2 = *(const bf16x8*)(vg + 2048);  // kc1, d 0-31
    bf16x8 vf3 = *(const bf16x8*)(vg + 3072);  // kc1, d 32-63
    const unsigned long long bits_n = mrow[(size_t)itn * 2048];

    // S^T = K_half * Q^T (32 keys x 32 q), K-dim 64 via 4 chained MFMAs.
    f32x16 st0;
#pragma unroll
    for (int i = 0; i < 16; ++i) st0[i] = 0.f;
    __builtin_amdgcn_s_setprio(1);
    st0 = MFMA32(kf0, qf[0], st0);
    st0 = MFMA32(kf1, qf[1], st0);
    st0 = MFMA32(kf2, qf[2], st0);
    st0 = MFMA32(kf3, qf[3], st0);
    __builtin_amdgcn_s_setprio(0);

    // p = exp2(s) raw (|s| bounded ~12); masked -> 0; per-(p,hh) denom.
    const unsigned kb32 = ((unsigned)(bits >> (32 * p))) >> (4 * hh);
    float Sl = 0.f;
#pragma unroll
    for (int r = 0; r < 16; ++r) {
      const int c = (r & 3) + 8 * (r >> 2);
      float p0 = __builtin_amdgcn_exp2f(st0[r]);
      p0 = ((kb32 >> c) & 1u) ? p0 : 0.f;
      st0[r] = p0;
      Sl += p0;
    }
    l_run += Sl;

    // O^T += V' * P: B-operand is P in NATURAL lane order (V' permuted to
    // match at prepass) — no cross-lane exchange.
#pragma unroll
    for (int kc = 0; kc < 2; ++kc) {
      union { unsigned u[4]; bf16x8 v; } bbv;
      bbv.u[0] = pk_trunc(st0[8 * kc + 0], st0[8 * kc + 1]);
      bbv.u[1] = pk_trunc(st0[8 * kc + 2], st0[8 * kc + 3]);
      bbv.u[2] = pk_trunc(st0[8 * kc + 4], st0[8 * kc + 5]);
      bbv.u[3] = pk_trunc(st0[8 * kc + 6], st0[8 * kc + 7]);
      __builtin_amdgcn_s_setprio(1);
      if (kc == 0) {
        acc0 = MFMA32(vf0, bbv.v, acc0);
        acc1 = MFMA32(vf1, bbv.v, acc1);
      } else {
        acc0 = MFMA32(vf2, bbv.v, acc0);
        acc1 = MFMA32(vf3, bbv.v, acc1);
      }
      __builtin_amdgcn_s_setprio(0);
    }

    kf0 = kn0; kf1 = kn1; kf2 = kn2; kf3 = kn3;
    bits = bits_n;
  }

  // Merge l partials over (p,hh) and key-half O partials; normalize; store.
  lsum[g][p][hh][col] = l_run;
  __syncthreads();
  const float scale = 1.f / (lsum[g][0][0][col] + lsum[g][0][1][col] +
                             lsum[g][1][0][col] + lsum[g][1][1][col]);

#pragma unroll
  for (int dt = 0; dt < 2; ++dt)
#pragma unroll
    for (int g2 = 0; g2 < 4; ++g2) {
      f32x4 w;
#pragma unroll
      for (int j = 0; j < 4; ++j)
        w[j] = (dt ? acc1[g2 * 4 + j] : acc0[g2 * 4 + j]) * scale;
      *(f32x4*)&Oe[p][g * 32 + col][g2 * 8 + hh * 4 + dt * 32] = w;
    }
  __syncthreads();
#pragma unroll
  for (int i = 0; i < 4; ++i) {
    const int idx = tid + i * 256;
    const int row = idx >> 4, c4 = idx & 15;
    f32x4 v0 = *(const f32x4*)&Oe[0][row][c4 * 4];
    f32x4 v1 = *(const f32x4*)&Oe[1][row][c4 * 4];
    f32x4 vs = v0 + v1;
    *(f32x4*)&outp[(size_t)(bh * L + q0 + row) * D + c4 * 4] = vs;
  }
}

// ---------------- fallback (no workspace): proven R2/R3 kernel ----------------
__global__ __launch_bounds__(256, 4) void nrev_attn_fb(
    const float* __restrict__ qp, const float* __restrict__ kp,
    const float* __restrict__ vp, const int* __restrict__ maskp,
    float* __restrict__ outp) {
  constexpr int L = 2048, D = 64;
  __shared__ union alignas(16) SMem {
    struct {
      bf16_t K[64 * 72];
      bf16_t V[64 * 72];
      unsigned long long mb[64];
    } s;
    float Oe[2][64][68];
  } sm;
  __shared__ float mlbuf[2][2][32][2];

  const int tid  = threadIdx.x;
  const int lane = tid & 63;
  const int wv   = tid >> 6;
  const int p    = wv >> 1;
  const int g    = wv & 1;
  const int col  = lane & 31;
  const int hh   = lane >> 5;
  const int blk  = blockIdx.x;
  const int bh   = (blk & 7) * 4 + (blk >> 8);
  const int qt   = (blk >> 3) & 31;
  const int bb   = bh >> 4;
  const int q0   = qt * 64;
  const float c1 = 0.18033688011112042f;

  bf16x8 qf[4];
  {
    const float* gq = qp + (size_t)(bh * L + q0 + g * 32 + col) * D;
#pragma unroll
    for (int dc = 0; dc < 4; ++dc) {
      const float* ptr = gq + dc * 16 + hh * 8;
      f32x4 f0 = *(const f32x4*)ptr;
      f32x4 f1 = *(const f32x4*)(ptr + 4);
      bf16x8 t;
#pragma unroll
      for (int j = 0; j < 4; ++j) {
        t[j]     = (bf16_t)(f0[j] * c1);
        t[4 + j] = (bf16_t)(f1[j] * c1);
      }
      qf[dc] = t;
    }
  }

  f32x16 acc0, acc1;
#pragma unroll
  for (int i = 0; i < 16; ++i) { acc0[i] = 0.f; acc1[i] = 0.f; }
  float m_run = -__builtin_inff();
  float l_run = 0.f;

  for (int kt = 0; kt < L; kt += 64) {
    __syncthreads();
    {
      const int key = tid >> 2, dp = tid & 3;
      const float* gk = kp + (size_t)(bh * L + kt + key) * D + dp * 16;
      f32x4 a0 = *(const f32x4*)gk;
      f32x4 a1 = *(const f32x4*)(gk + 4);
      f32x4 a2 = *(const f32x4*)(gk + 8);
      f32x4 a3 = *(const f32x4*)(gk + 12);
      bf16x8 w0, w1;
#pragma unroll
      for (int j = 0; j < 4; ++j) {
        w0[j] = (bf16_t)a0[j]; w0[4 + j] = (bf16_t)a1[j];
        w1[j] = (bf16_t)a2[j]; w1[4 + j] = (bf16_t)a3[j];
      }
      *(bf16x8*)&sm.s.K[key * 72 + dp * 16]     = w0;
      *(bf16x8*)&sm.s.K[key * 72 + dp * 16 + 8] = w1;
    }
    {
      const int w16 = wv * 16;
      const float* gv = vp + (size_t)(bh * L + kt + w16) * D + lane;
      bf16x8 w0, w1;
#pragma unroll
      for (int i = 0; i < 8; ++i) {
        w0[i] = (bf16_t)fminf(gv[(size_t)i * D], 0.f);
        w1[i] = (bf16_t)fminf(gv[(size_t)(i + 8) * D], 0.f);
      }
      *(bf16x8*)&sm.s.V[lane * 72 + w16]     = w0;
      *(bf16x8*)&sm.s.V[lane * 72 + w16 + 8] = w1;
    }
    for (int i = 0; i < 16; ++i) {
      const int row = wv * 16 + i;
      int mv = maskp[(size_t)bb * L * L + (size_t)(q0 + row) * L + kt + lane];
      unsigned long long bal = __ballot(mv != 0);
      if (lane == 0) sm.s.mb[row] = bal;
    }
    __syncthreads();

    f32x16 st0;
#pragma unroll
    for (int i = 0; i < 16; ++i) st0[i] = 0.f;
#pragma unroll
    for (int dc = 0; dc < 4; ++dc) {
      bf16x8 a0 = *(const bf16x8*)&sm.s.K[(p * 32 + col) * 72 + dc * 16 + hh * 8];
      st0 = MFMA32(a0, qf[dc], st0);
    }

    float M = st0[0];
#pragma unroll
    for (int r = 1; r < 16; ++r) M = fmaxf(M, st0[r]);
#pragma unroll
    for (int sh = 1; sh < 64; sh <<= 1) M = fmaxf(M, __shfl_xor(M, sh));
    if (M > m_run) {
      const float alpha = exp2f(m_run - M);
      l_run *= alpha;
#pragma unroll
      for (int r = 0; r < 16; ++r) { acc0[r] *= alpha; acc1[r] *= alpha; }
      m_run = M;
    }

    const unsigned long long bits = sm.s.mb[g * 32 + col];
    const unsigned kb = ((unsigned)(bits >> (32 * p))) >> (4 * hh);
    float Sl = 0.f;
#pragma unroll
    for (int r = 0; r < 16; ++r) {
      const int c = (r & 3) + 8 * (r >> 2);
      float p0 = exp2f(st0[r] - m_run);
      p0 = ((kb >> c) & 1u) ? p0 : 0.f;
      st0[r] = p0;
      Sl += p0;
    }
    Sl += __shfl_xor(Sl, 32);
    l_run += Sl;

#pragma unroll
    for (int kc = 0; kc < 2; ++kc) {
      const unsigned pk0  = pk_bf16(st0[8 * kc + 0], st0[8 * kc + 1]);
      const unsigned pk0b = pk_bf16(st0[8 * kc + 2], st0[8 * kc + 3]);
      const unsigned pk1  = pk_bf16(st0[8 * kc + 4], st0[8 * kc + 5]);
      const unsigned pk1b = pk_bf16(st0[8 * kc + 6], st0[8 * kc + 7]);
      const unsigned sh0  = __shfl_xor(pk0, 32);
      const unsigned sh0b = __shfl_xor(pk0b, 32);
      const unsigned sh1  = __shfl_xor(pk1, 32);
      const unsigned sh1b = __shfl_xor(pk1b, 32);
      union { unsigned u[4]; bf16x8 v; } bbv;
      bbv.u[0] = hh ? sh1  : pk0;
      bbv.u[1] = hh ? sh1b : pk0b;
      bbv.u[2] = hh ? pk1  : sh0;
      bbv.u[3] = hh ? pk1b : sh0b;
      const int kbase = p * 32 + kc * 16 + hh * 8;
      bf16x8 av0 = *(const bf16x8*)&sm.s.V[col * 72        + kbase];
      bf16x8 av1 = *(const bf16x8*)&sm.s.V[(col + 32) * 72 + kbase];
      acc0 = MFMA32(av0, bbv.v, acc0);
      acc1 = MFMA32(av1, bbv.v, acc1);
    }
  }

  if (hh == 0) {
    mlbuf[g][p][col][0] = m_run;
    mlbuf[g][p][col][1] = l_run;
  }
  __syncthreads();
  const float m0 = mlbuf[g][0][col][0], l0v = mlbuf[g][0][col][1];
  const float m1 = mlbuf[g][1][col][0], l1v = mlbuf[g][1][col][1];
  const float ms = fmaxf(m0, m1);
  const float a0s = exp2f(m0 - ms), a1s = exp2f(m1 - ms);
  const float lst = a0s * l0v + a1s * l1v;
  const float scale = (p ? a1s : a0s) / lst;

#pragma unroll
  for (int dt = 0; dt < 2; ++dt)
#pragma unroll
    for (int g2 = 0; g2 < 4; ++g2) {
      f32x4 w;
#pragma unroll
      for (int j = 0; j < 4; ++j)
        w[j] = (dt ? acc1[g2 * 4 + j] : acc0[g2 * 4 + j]) * scale;
      *(f32x4*)&sm.Oe[p][g * 32 + col][g2 * 8 + hh * 4 + dt * 32] = w;
    }
  __syncthreads();
#pragma unroll
  for (int i = 0; i < 4; ++i) {
    const int idx = tid + i * 256;
    const int row = idx >> 4, c4 = idx & 15;
    f32x4 v0 = *(const f32x4*)&sm.Oe[0][row][c4 * 4];
    f32x4 v1 = *(const f32x4*)&sm.Oe[1][row][c4 * 4];
    f32x4 vs = v0 + v1;
    *(f32x4*)&outp[(size_t)(bh * L + q0 + row) * D + c4 * 4] = vs;
  }
}

extern "C" void kernel_launch(void* const* d_in, const int* in_sizes, int n_in,
                              void* d_out, int out_size, void* d_ws, size_t ws_size,
                              hipStream_t stream) {
  (void)in_sizes; (void)n_in; (void)out_size;
  const float* qp = (const float*)d_in[0];
  const float* kp = (const float*)d_in[1];
  const float* vp = (const float*)d_in[2];
  const int*   mp = (const int*)d_in[3];
  float* op = (float*)d_out;

  // ws layout: K' frag bf16 8 MiB | V' frag bf16 8 MiB | mask words 1 MiB
  const size_t kOff = 0;
  const size_t vOff = (size_t)8 * 1024 * 1024;
  const size_t mOff = (size_t)16 * 1024 * 1024;
  const size_t need = mOff + (size_t)1024 * 1024;

  if (d_ws != nullptr && ws_size >= need) {
    bf16_t* kb = (bf16_t*)((char*)d_ws + kOff);
    bf16_t* vt = (bf16_t*)((char*)d_ws + vOff);
    unsigned long long* mpk = (unsigned long long*)((char*)d_ws + mOff);
    hipLaunchKernelGGL(prepass, dim3(6144), dim3(256), 0, stream,
                       kp, vp, mp, kb, vt, mpk);
    hipLaunchKernelGGL(nrev_attn_ws8, dim3(1024), dim3(256), 0, stream,
                       qp, kb, vt, mpk, op);
  } else {
    hipLaunchKernelGGL(nrev_attn_fb, dim3(1024), dim3(256), 0, stream,
                       qp, kp, vp, mp, op);
  }
}

// Round 8
// 161.827 us; speedup vs baseline: 1.0478x; 1.0024x over previous
//
#include <hip/hip_runtime.h>
#include <math.h>

typedef __bf16 bf16_t;
typedef bf16_t bf16x8 __attribute__((ext_vector_type(8)));
typedef float  f32x16 __attribute__((ext_vector_type(16)));
typedef float  f32x4  __attribute__((ext_vector_type(4)));

#define MFMA32(a, b, c) __builtin_amdgcn_mfma_f32_32x32x16_bf16((a), (b), (c), 0, 0, 0)

static __device__ __forceinline__ unsigned pk_bf16(float a, float b) {
  union { bf16_t h[2]; unsigned u; } t;
  t.h[0] = (bf16_t)a;
  t.h[1] = (bf16_t)b;
  return t.u;
}

// Truncating bf16 pair pack: lo16 = a[31:16], hi16 = b[31:16]. 2 VALU ops.
static __device__ __forceinline__ unsigned pk_trunc(float a, float b) {
  return (__float_as_uint(a) >> 16) | (__float_as_uint(b) & 0xFFFF0000u);
}

// ---------------- fused prepass ----------------
// Sect 0: K fp32 -> K' bf16 QK-A-fragment order:
//   K'[bh][kh(64)][dc(4)][lane(64)][j(8)] = K[bh][kh*32+(lane&31)][dc*16+(lane>>5)*8+j]
// Sect 1: V fp32 -> neg-relu bf16 V' PV-A-fragment order WITH the key
//   permutation matching P's natural post-QK lane order (kills the in-loop
//   lane^32 exchange): within each 16-key group, logical slot (hh,j) holds
//   actual key perm = hh*4 + (j&3) + 8*(j>>2).
//   V'[bh][kt(32)][p(2)][kc(2)][rr(2)][lane(64)][j(8)]
//     = min(V,0)^T[rr*32+(lane&31)][kt*64+p*32+kc*16+perm((lane>>5),j)]
// Sect 2: mask int32 (B,1,L,L) -> u64 words [b][kw(32)][q(2048)]
__global__ __launch_bounds__(256) void prepass(
    const float* __restrict__ kp, const float* __restrict__ vp,
    const int* __restrict__ maskp, bf16_t* __restrict__ kfr,
    bf16_t* __restrict__ vfr, unsigned long long* __restrict__ mpk) {
  const int sect = blockIdx.x >> 11;
  const int blk  = blockIdx.x & 2047;
  const int tid  = threadIdx.x;

  if (sect == 0) {
    const size_t t = (size_t)blk * 256 + tid;
    const int ln = t & 63, dc = (t >> 6) & 3;
    const int kh = (t >> 8) & 63, bh = (int)(t >> 14);
    const float* s = kp + ((size_t)(bh * 2048 + kh * 32 + (ln & 31))) * 64 +
                     dc * 16 + (ln >> 5) * 8;
    f32x4 a0 = *(const f32x4*)s;
    f32x4 a1 = *(const f32x4*)(s + 4);
    bf16x8 w;
#pragma unroll
    for (int j = 0; j < 4; ++j) { w[j] = (bf16_t)a0[j]; w[4 + j] = (bf16_t)a1[j]; }
    *(bf16x8*)(kfr + t * 8) = w;
  } else if (sect == 1) {
    const size_t t = (size_t)blk * 256 + tid;
    const int ln = t & 63, rr = (t >> 6) & 1, kc = (t >> 7) & 1;
    const int p = (t >> 8) & 1, kt = (t >> 9) & 31, bh = (int)(t >> 14);
    const int d    = rr * 32 + (ln & 31);
    const int hh   = ln >> 5;
    const int kb   = kt * 64 + p * 32 + kc * 16;  // 16-key group base
    const float* s = vp + ((size_t)(bh * 2048 + kb)) * 64 + d;
    bf16_t w[8];
#pragma unroll
    for (int j = 0; j < 8; ++j) {
      const int key = hh * 4 + (j & 3) + 8 * (j >> 2);  // perm
      w[j] = (bf16_t)fminf(s[(size_t)key * 64], 0.f);
    }
    *(bf16x8*)(vfr + t * 8) = *(bf16x8*)w;
  } else {
    const int lane = tid & 63;
    const int gw   = blk * 4 + (tid >> 6);
    const int bq   = gw >> 1, half = gw & 1;
    const int b    = bq >> 11, q = bq & 2047;
    const size_t base = (size_t)bq * 2048 + half * 1024;
    unsigned long long w = 0;
#pragma unroll
    for (int j = 0; j < 16; ++j) {
      const int mv = maskp[base + j * 64 + lane];
      const unsigned long long bal = __ballot(mv != 0);
      if (lane == j) w = bal;
    }
    if (lane < 16) mpk[((size_t)b * 32 + half * 16 + lane) * 2048 + q] = w;
  }
}

// ---------------- main kernel (R0-proven optimum, restored verbatim) --------
// Session verdict (9 variants, rounds 0-7): this barrier-free 64-q schedule
// (56.5 us) is a sharp local optimum. Regressions measured against it:
//   expanded AND-mask +9.5 | bias-init+MFMA-denom +6.9 | 8-wave cap: spill
//   two-chain pipeline +6.4 | V-prefetch +2.5 | 32-q/2048-grid +9.3
//   s_setprio on MFMA clusters +3.2
// Counters at optimum: MfmaUtil 24.7% (= exact MFMA pipe arithmetic:
// 4w*32it*8mfma*32cyc/SIMD), VALUBusy 52%, HBM 7%. Absolute VALU-busy cycles
// are invariant (~70k) under instruction-count cuts -> the floor is the
// scheduling equilibrium of the uniform 4-wave braid (shared VALU issue +
// L2-return latency), which the compiler's schedule of THIS body navigates
// better than any source-level restructure. Do not perturb without a
// mechanism that changes the braid itself (inline-asm full-loop scheduling).
__global__ __launch_bounds__(256, 4) void nrev_attn_ws(
    const float* __restrict__ qp, const bf16_t* __restrict__ kfr,
    const bf16_t* __restrict__ vfr, const unsigned long long* __restrict__ mpk,
    float* __restrict__ outp) {
  constexpr int L = 2048, D = 64;
  __shared__ float Oe[2][64][68];
  __shared__ float lsum[2][2][2][32];   // [g][p][hh][col]

  const int tid  = threadIdx.x;
  const int lane = tid & 63;
  const int wv   = tid >> 6;
  const int p    = wv >> 1;
  const int g    = wv & 1;
  const int col  = lane & 31;
  const int hh   = lane >> 5;
  const int blk  = blockIdx.x;
  const int bh   = (blk & 7) * 4 + (blk >> 8);   // XCD swizzle (R2: FETCH 5x cut)
  const int qt   = (blk >> 3) & 31;
  const int bb   = bh >> 4;
  const int q0   = qt * 64;
  const float c1 = 0.18033688011112042f;  // 0.125 * log2(e), folded into Q

  // Q fragments (B-operand of S^T = K*Q^T).
  bf16x8 qf[4];
  {
    const float* gq = qp + (size_t)(bh * L + q0 + g * 32 + col) * D;
#pragma unroll
    for (int dc = 0; dc < 4; ++dc) {
      const float* ptr = gq + dc * 16 + hh * 8;
      f32x4 f0 = *(const f32x4*)ptr;
      f32x4 f1 = *(const f32x4*)(ptr + 4);
      bf16x8 t;
#pragma unroll
      for (int j = 0; j < 4; ++j) {
        t[j]     = (bf16_t)(f0[j] * c1);
        t[4 + j] = (bf16_t)(f1[j] * c1);
      }
      qf[dc] = t;
    }
  }

  const char* kpt = (const char*)kfr + (size_t)bh * 262144 + p * 4096 + (size_t)lane * 16;
  const char* vpt = (const char*)vfr + (size_t)bh * 262144 + p * 4096 + (size_t)lane * 16;
  const unsigned long long* mrow = mpk + (size_t)bb * 65536 + q0 + g * 32 + col;

  f32x16 acc0, acc1;
#pragma unroll
  for (int i = 0; i < 16; ++i) { acc0[i] = 0.f; acc1[i] = 0.f; }
  float l_run = 0.f;  // partial over own (p,hh) keys only; merged in epilogue

  bf16x8 kf0 = *(const bf16x8*)(kpt + 0);
  bf16x8 kf1 = *(const bf16x8*)(kpt + 1024);
  bf16x8 kf2 = *(const bf16x8*)(kpt + 2048);
  bf16x8 kf3 = *(const bf16x8*)(kpt + 3072);
  unsigned long long bits = mrow[0];

  for (int it = 0; it < 32; ++it) {
    const int itn = (it < 31) ? it + 1 : 31;  // clamped; value unused last iter
    const char* kn = kpt + (size_t)itn * 8192;
    bf16x8 kn0 = *(const bf16x8*)(kn + 0);
    bf16x8 kn1 = *(const bf16x8*)(kn + 1024);
    bf16x8 kn2 = *(const bf16x8*)(kn + 2048);
    bf16x8 kn3 = *(const bf16x8*)(kn + 3072);
    const char* vg = vpt + (size_t)it * 8192;
    bf16x8 vf0 = *(const bf16x8*)(vg + 0);     // kc0, d 0-31
    bf16x8 vf1 = *(const bf16x8*)(vg + 1024);  // kc0, d 32-63
    bf16x8 vf2 = *(const bf16x8*)(vg + 2048);  // kc1, d 0-31
    bf16x8 vf3 = *(const bf16x8*)(vg + 3072);  // kc1, d 32-63
    const unsigned long long bits_n = mrow[(size_t)itn * 2048];

    // S^T = K_half * Q^T (32 keys x 32 q), K-dim 64 via 4 chained MFMAs.
    f32x16 st0;
#pragma unroll
    for (int i = 0; i < 16; ++i) st0[i] = 0.f;
    st0 = MFMA32(kf0, qf[0], st0);
    st0 = MFMA32(kf1, qf[1], st0);
    st0 = MFMA32(kf2, qf[2], st0);
    st0 = MFMA32(kf3, qf[3], st0);

    // p = exp2(s) raw (|s| bounded ~12); masked -> 0; per-(p,hh) denom.
    const unsigned kb32 = ((unsigned)(bits >> (32 * p))) >> (4 * hh);
    float Sl = 0.f;
#pragma unroll
    for (int r = 0; r < 16; ++r) {
      const int c = (r & 3) + 8 * (r >> 2);
      float p0 = __builtin_amdgcn_exp2f(st0[r]);
      p0 = ((kb32 >> c) & 1u) ? p0 : 0.f;
      st0[r] = p0;
      Sl += p0;
    }
    l_run += Sl;

    // O^T += V' * P: B-operand is P in NATURAL lane order (V' permuted to
    // match at prepass) — no cross-lane exchange.
#pragma unroll
    for (int kc = 0; kc < 2; ++kc) {
      union { unsigned u[4]; bf16x8 v; } bbv;
      bbv.u[0] = pk_trunc(st0[8 * kc + 0], st0[8 * kc + 1]);
      bbv.u[1] = pk_trunc(st0[8 * kc + 2], st0[8 * kc + 3]);
      bbv.u[2] = pk_trunc(st0[8 * kc + 4], st0[8 * kc + 5]);
      bbv.u[3] = pk_trunc(st0[8 * kc + 6], st0[8 * kc + 7]);
      if (kc == 0) {
        acc0 = MFMA32(vf0, bbv.v, acc0);
        acc1 = MFMA32(vf1, bbv.v, acc1);
      } else {
        acc0 = MFMA32(vf2, bbv.v, acc0);
        acc1 = MFMA32(vf3, bbv.v, acc1);
      }
    }

    kf0 = kn0; kf1 = kn1; kf2 = kn2; kf3 = kn3;
    bits = bits_n;
  }

  // Merge l partials over (p,hh) and key-half O partials; normalize; store.
  lsum[g][p][hh][col] = l_run;
  __syncthreads();
  const float scale = 1.f / (lsum[g][0][0][col] + lsum[g][0][1][col] +
                             lsum[g][1][0][col] + lsum[g][1][1][col]);

#pragma unroll
  for (int dt = 0; dt < 2; ++dt)
#pragma unroll
    for (int g2 = 0; g2 < 4; ++g2) {
      f32x4 w;
#pragma unroll
      for (int j = 0; j < 4; ++j)
        w[j] = (dt ? acc1[g2 * 4 + j] : acc0[g2 * 4 + j]) * scale;
      *(f32x4*)&Oe[p][g * 32 + col][g2 * 8 + hh * 4 + dt * 32] = w;
    }
  __syncthreads();
#pragma unroll
  for (int i = 0; i < 4; ++i) {
    const int idx = tid + i * 256;
    const int row = idx >> 4, c4 = idx & 15;
    f32x4 v0 = *(const f32x4*)&Oe[0][row][c4 * 4];
    f32x4 v1 = *(const f32x4*)&Oe[1][row][c4 * 4];
    f32x4 vs = v0 + v1;
    *(f32x4*)&outp[(size_t)(bh * L + q0 + row) * D + c4 * 4] = vs;
  }
}

// ---------------- fallback (no workspace): proven R2/R3 kernel ----------------
__global__ __launch_bounds__(256, 4) void nrev_attn_fb(
    const float* __restrict__ qp, const float* __restrict__ kp,
    const float* __restrict__ vp, const int* __restrict__ maskp,
    float* __restrict__ outp) {
  constexpr int L = 2048, D = 64;
  __shared__ union alignas(16) SMem {
    struct {
      bf16_t K[64 * 72];
      bf16_t V[64 * 72];
      unsigned long long mb[64];
    } s;
    float Oe[2][64][68];
  } sm;
  __shared__ float mlbuf[2][2][32][2];

  const int tid  = threadIdx.x;
  const int lane = tid & 63;
  const int wv   = tid >> 6;
  const int p    = wv >> 1;
  const int g    = wv & 1;
  const int col  = lane & 31;
  const int hh   = lane >> 5;
  const int blk  = blockIdx.x;
  const int bh   = (blk & 7) * 4 + (blk >> 8);
  const int qt   = (blk >> 3) & 31;
  const int bb   = bh >> 4;
  const int q0   = qt * 64;
  const float c1 = 0.18033688011112042f;

  bf16x8 qf[4];
  {
    const float* gq = qp + (size_t)(bh * L + q0 + g * 32 + col) * D;
#pragma unroll
    for (int dc = 0; dc < 4; ++dc) {
      const float* ptr = gq + dc * 16 + hh * 8;
      f32x4 f0 = *(const f32x4*)ptr;
      f32x4 f1 = *(const f32x4*)(ptr + 4);
      bf16x8 t;
#pragma unroll
      for (int j = 0; j < 4; ++j) {
        t[j]     = (bf16_t)(f0[j] * c1);
        t[4 + j] = (bf16_t)(f1[j] * c1);
      }
      qf[dc] = t;
    }
  }

  f32x16 acc0, acc1;
#pragma unroll
  for (int i = 0; i < 16; ++i) { acc0[i] = 0.f; acc1[i] = 0.f; }
  float m_run = -__builtin_inff();
  float l_run = 0.f;

  for (int kt = 0; kt < L; kt += 64) {
    __syncthreads();
    {
      const int key = tid >> 2, dp = tid & 3;
      const float* gk = kp + (size_t)(bh * L + kt + key) * D + dp * 16;
      f32x4 a0 = *(const f32x4*)gk;
      f32x4 a1 = *(const f32x4*)(gk + 4);
      f32x4 a2 = *(const f32x4*)(gk + 8);
      f32x4 a3 = *(const f32x4*)(gk + 12);
      bf16x8 w0, w1;
#pragma unroll
      for (int j = 0; j < 4; ++j) {
        w0[j] = (bf16_t)a0[j]; w0[4 + j] = (bf16_t)a1[j];
        w1[j] = (bf16_t)a2[j]; w1[4 + j] = (bf16_t)a3[j];
      }
      *(bf16x8*)&sm.s.K[key * 72 + dp * 16]     = w0;
      *(bf16x8*)&sm.s.K[key * 72 + dp * 16 + 8] = w1;
    }
    {
      const int w16 = wv * 16;
      const float* gv = vp + (size_t)(bh * L + kt + w16) * D + lane;
      bf16x8 w0, w1;
#pragma unroll
      for (int i = 0; i < 8; ++i) {
        w0[i] = (bf16_t)fminf(gv[(size_t)i * D], 0.f);
        w1[i] = (bf16_t)fminf(gv[(size_t)(i + 8) * D], 0.f);
      }
      *(bf16x8*)&sm.s.V[lane * 72 + w16]     = w0;
      *(bf16x8*)&sm.s.V[lane * 72 + w16 + 8] = w1;
    }
    for (int i = 0; i < 16; ++i) {
      const int row = wv * 16 + i;
      int mv = maskp[(size_t)bb * L * L + (size_t)(q0 + row) * L + kt + lane];
      unsigned long long bal = __ballot(mv != 0);
      if (lane == 0) sm.s.mb[row] = bal;
    }
    __syncthreads();

    f32x16 st0;
#pragma unroll
    for (int i = 0; i < 16; ++i) st0[i] = 0.f;
#pragma unroll
    for (int dc = 0; dc < 4; ++dc) {
      bf16x8 a0 = *(const bf16x8*)&sm.s.K[(p * 32 + col) * 72 + dc * 16 + hh * 8];
      st0 = MFMA32(a0, qf[dc], st0);
    }

    float M = st0[0];
#pragma unroll
    for (int r = 1; r < 16; ++r) M = fmaxf(M, st0[r]);
#pragma unroll
    for (int sh = 1; sh < 64; sh <<= 1) M = fmaxf(M, __shfl_xor(M, sh));
    if (M > m_run) {
      const float alpha = exp2f(m_run - M);
      l_run *= alpha;
#pragma unroll
      for (int r = 0; r < 16; ++r) { acc0[r] *= alpha; acc1[r] *= alpha; }
      m_run = M;
    }

    const unsigned long long bits = sm.s.mb[g * 32 + col];
    const unsigned kb = ((unsigned)(bits >> (32 * p))) >> (4 * hh);
    float Sl = 0.f;
#pragma unroll
    for (int r = 0; r < 16; ++r) {
      const int c = (r & 3) + 8 * (r >> 2);
      float p0 = exp2f(st0[r] - m_run);
      p0 = ((kb >> c) & 1u) ? p0 : 0.f;
      st0[r] = p0;
      Sl += p0;
    }
    Sl += __shfl_xor(Sl, 32);
    l_run += Sl;

#pragma unroll
    for (int kc = 0; kc < 2; ++kc) {
      const unsigned pk0  = pk_bf16(st0[8 * kc + 0], st0[8 * kc + 1]);
      const unsigned pk0b = pk_bf16(st0[8 * kc + 2], st0[8 * kc + 3]);
      const unsigned pk1  = pk_bf16(st0[8 * kc + 4], st0[8 * kc + 5]);
      const unsigned pk1b = pk_bf16(st0[8 * kc + 6], st0[8 * kc + 7]);
      const unsigned sh0  = __shfl_xor(pk0, 32);
      const unsigned sh0b = __shfl_xor(pk0b, 32);
      const unsigned sh1  = __shfl_xor(pk1, 32);
      const unsigned sh1b = __shfl_xor(pk1b, 32);
      union { unsigned u[4]; bf16x8 v; } bbv;
      bbv.u[0] = hh ? sh1  : pk0;
      bbv.u[1] = hh ? sh1b : pk0b;
      bbv.u[2] = hh ? pk1  : sh0;
      bbv.u[3] = hh ? pk1b : sh0b;
      const int kbase = p * 32 + kc * 16 + hh * 8;
      bf16x8 av0 = *(const bf16x8*)&sm.s.V[col * 72        + kbase];
      bf16x8 av1 = *(const bf16x8*)&sm.s.V[(col + 32) * 72 + kbase];
      acc0 = MFMA32(av0, bbv.v, acc0);
      acc1 = MFMA32(av1, bbv.v, acc1);
    }
  }

  if (hh == 0) {
    mlbuf[g][p][col][0] = m_run;
    mlbuf[g][p][col][1] = l_run;
  }
  __syncthreads();
  const float m0 = mlbuf[g][0][col][0], l0v = mlbuf[g][0][col][1];
  const float m1 = mlbuf[g][1][col][0], l1v = mlbuf[g][1][col][1];
  const float ms = fmaxf(m0, m1);
  const float a0s = exp2f(m0 - ms), a1s = exp2f(m1 - ms);
  const float lst = a0s * l0v + a1s * l1v;
  const float scale = (p ? a1s : a0s) / lst;

#pragma unroll
  for (int dt = 0; dt < 2; ++dt)
#pragma unroll
    for (int g2 = 0; g2 < 4; ++g2) {
      f32x4 w;
#pragma unroll
      for (int j = 0; j < 4; ++j)
        w[j] = (dt ? acc1[g2 * 4 + j] : acc0[g2 * 4 + j]) * scale;
      *(f32x4*)&sm.Oe[p][g * 32 + col][g2 * 8 + hh * 4 + dt * 32] = w;
    }
  __syncthreads();
#pragma unroll
  for (int i = 0; i < 4; ++i) {
    const int idx = tid + i * 256;
    const int row = idx >> 4, c4 = idx & 15;
    f32x4 v0 = *(const f32x4*)&sm.Oe[0][row][c4 * 4];
    f32x4 v1 = *(const f32x4*)&sm.Oe[1][row][c4 * 4];
    f32x4 vs = v0 + v1;
    *(f32x4*)&outp[(size_t)(bh * L + q0 + row) * D + c4 * 4] = vs;
  }
}

extern "C" void kernel_launch(void* const* d_in, const int* in_sizes, int n_in,
                              void* d_out, int out_size, void* d_ws, size_t ws_size,
                              hipStream_t stream) {
  (void)in_sizes; (void)n_in; (void)out_size;
  const float* qp = (const float*)d_in[0];
  const float* kp = (const float*)d_in[1];
  const float* vp = (const float*)d_in[2];
  const int*   mp = (const int*)d_in[3];
  float* op = (float*)d_out;

  // ws layout: K' frag bf16 8 MiB | V' frag bf16 8 MiB | mask words 1 MiB
  const size_t kOff = 0;
  const size_t vOff = (size_t)8 * 1024 * 1024;
  const size_t mOff = (size_t)16 * 1024 * 1024;
  const size_t need = mOff + (size_t)1024 * 1024;

  if (d_ws != nullptr && ws_size >= need) {
    bf16_t* kb = (bf16_t*)((char*)d_ws + kOff);
    bf16_t* vt = (bf16_t*)((char*)d_ws + vOff);
    unsigned long long* mpk = (unsigned long long*)((char*)d_ws + mOff);
    hipLaunchKernelGGL(prepass, dim3(6144), dim3(256), 0, stream,
                       kp, vp, mp, kb, vt, mpk);
    hipLaunchKernelGGL(nrev_attn_ws, dim3(1024), dim3(256), 0, stream,
                       qp, kb, vt, mpk, op);
  } else {
    hipLaunchKernelGGL(nrev_attn_fb, dim3(1024), dim3(256), 0, stream,
                       qp, kp, vp, mp, op);
  }
}

// Round 9
// 160.480 us; speedup vs baseline: 1.0566x; 1.0084x over previous
//
#include <hip/hip_runtime.h>
#include <math.h>

typedef __bf16 bf16_t;
typedef bf16_t bf16x8 __attribute__((ext_vector_type(8)));
typedef float  f32x16 __attribute__((ext_vector_type(16)));
typedef float  f32x4  __attribute__((ext_vector_type(4)));

#define MFMA32(a, b, c) __builtin_amdgcn_mfma_f32_32x32x16_bf16((a), (b), (c), 0, 0, 0)

static __device__ __forceinline__ unsigned pk_bf16(float a, float b) {
  union { bf16_t h[2]; unsigned u; } t;
  t.h[0] = (bf16_t)a;
  t.h[1] = (bf16_t)b;
  return t.u;
}

// Truncating bf16 pair pack: lo16 = a[31:16], hi16 = b[31:16]. 2 VALU ops.
static __device__ __forceinline__ unsigned pk_trunc(float a, float b) {
  return (__float_as_uint(a) >> 16) | (__float_as_uint(b) & 0xFFFF0000u);
}

// 1-bit sign-smear: returns 0x00000000 or 0xFFFFFFFF from bit `pos` of w.
static __device__ __forceinline__ int bit_smear(unsigned w, int pos) {
#if __has_builtin(__builtin_amdgcn_sbfe)
  return __builtin_amdgcn_sbfe((int)w, pos, 1);
#else
  return ((int)(w << (31 - pos))) >> 31;
#endif
}

// ---------------- fused prepass (R0-proven, byte-identical) ----------------
// Sect 0: K fp32 -> K' bf16 QK-A-fragment order:
//   K'[bh][kh(64)][dc(4)][lane(64)][j(8)] = K[bh][kh*32+(lane&31)][dc*16+(lane>>5)*8+j]
// Sect 1: V fp32 -> neg-relu bf16 V' PV-A-fragment order WITH the key
//   permutation matching P's natural post-QK lane order.
// Sect 2: mask int32 (B,1,L,L) -> u64 words [b][kw(32)][q(2048)]
__global__ __launch_bounds__(256) void prepass(
    const float* __restrict__ kp, const float* __restrict__ vp,
    const int* __restrict__ maskp, bf16_t* __restrict__ kfr,
    bf16_t* __restrict__ vfr, unsigned long long* __restrict__ mpk) {
  const int sect = blockIdx.x >> 11;
  const int blk  = blockIdx.x & 2047;
  const int tid  = threadIdx.x;

  if (sect == 0) {
    const size_t t = (size_t)blk * 256 + tid;
    const int ln = t & 63, dc = (t >> 6) & 3;
    const int kh = (t >> 8) & 63, bh = (int)(t >> 14);
    const float* s = kp + ((size_t)(bh * 2048 + kh * 32 + (ln & 31))) * 64 +
                     dc * 16 + (ln >> 5) * 8;
    f32x4 a0 = *(const f32x4*)s;
    f32x4 a1 = *(const f32x4*)(s + 4);
    bf16x8 w;
#pragma unroll
    for (int j = 0; j < 4; ++j) { w[j] = (bf16_t)a0[j]; w[4 + j] = (bf16_t)a1[j]; }
    *(bf16x8*)(kfr + t * 8) = w;
  } else if (sect == 1) {
    const size_t t = (size_t)blk * 256 + tid;
    const int ln = t & 63, rr = (t >> 6) & 1, kc = (t >> 7) & 1;
    const int p = (t >> 8) & 1, kt = (t >> 9) & 31, bh = (int)(t >> 14);
    const int d    = rr * 32 + (ln & 31);
    const int hh   = ln >> 5;
    const int kb   = kt * 64 + p * 32 + kc * 16;  // 16-key group base
    const float* s = vp + ((size_t)(bh * 2048 + kb)) * 64 + d;
    bf16_t w[8];
#pragma unroll
    for (int j = 0; j < 8; ++j) {
      const int key = hh * 4 + (j & 3) + 8 * (j >> 2);  // perm
      w[j] = (bf16_t)fminf(s[(size_t)key * 64], 0.f);
    }
    *(bf16x8*)(vfr + t * 8) = *(bf16x8*)w;
  } else {
    const int lane = tid & 63;
    const int gw   = blk * 4 + (tid >> 6);
    const int bq   = gw >> 1, half = gw & 1;
    const int b    = bq >> 11, q = bq & 2047;
    const size_t base = (size_t)bq * 2048 + half * 1024;
    unsigned long long w = 0;
#pragma unroll
    for (int j = 0; j < 16; ++j) {
      const int mv = maskp[base + j * 64 + lane];
      const unsigned long long bal = __ballot(mv != 0);
      if (lane == j) w = bal;
    }
    if (lane < 16) mpk[((size_t)b * 32 + half * 16 + lane) * 2048 + q] = w;
  }
}

// ---------------- main kernel v9: R0 body, mask moved to accumulator init ----
// Single-variable A/B vs the R0 optimum (56.5 us): masking relocated from
// AFTER exp2 (bfe+cmp+cndmask per element, 48 ops on the serial tail into
// pack/PV) to the st0 INIT (2 ops/elem: sbfe(~kb32,c,1) & -16384.0f; the
// bias rides through the chained QK MFMAs and exp2(s-16384) underflows to
// exact 0 — |s| <= ~300 so margin is ~16000x). Visible elements init to 0.0
// -> bitwise-identical outputs to R0. Net -32 VALU ops/iter AND a ~100-cycle
// shorter post-exp2 dependency chain. Everything else (prepass u64 words,
// loads, pk_trunc, Sl sum, epilogue, launch config) byte-identical to R0.
// Prior probes of bias-init (R2/R4/R6) were confounded with accL-MFMAs /
// pipeline / tile restructures that each independently cost ~6 us.
__global__ __launch_bounds__(256, 4) void nrev_attn_ws(
    const float* __restrict__ qp, const bf16_t* __restrict__ kfr,
    const bf16_t* __restrict__ vfr, const unsigned long long* __restrict__ mpk,
    float* __restrict__ outp) {
  constexpr int L = 2048, D = 64;
  __shared__ float Oe[2][64][68];
  __shared__ float lsum[2][2][2][32];   // [g][p][hh][col]

  const int tid  = threadIdx.x;
  const int lane = tid & 63;
  const int wv   = tid >> 6;
  const int p    = wv >> 1;
  const int g    = wv & 1;
  const int col  = lane & 31;
  const int hh   = lane >> 5;
  const int blk  = blockIdx.x;
  const int bh   = (blk & 7) * 4 + (blk >> 8);   // XCD swizzle (R2: FETCH 5x cut)
  const int qt   = (blk >> 3) & 31;
  const int bb   = bh >> 4;
  const int q0   = qt * 64;
  const float c1 = 0.18033688011112042f;  // 0.125 * log2(e), folded into Q

  // Q fragments (B-operand of S^T = K*Q^T).
  bf16x8 qf[4];
  {
    const float* gq = qp + (size_t)(bh * L + q0 + g * 32 + col) * D;
#pragma unroll
    for (int dc = 0; dc < 4; ++dc) {
      const float* ptr = gq + dc * 16 + hh * 8;
      f32x4 f0 = *(const f32x4*)ptr;
      f32x4 f1 = *(const f32x4*)(ptr + 4);
      bf16x8 t;
#pragma unroll
      for (int j = 0; j < 4; ++j) {
        t[j]     = (bf16_t)(f0[j] * c1);
        t[4 + j] = (bf16_t)(f1[j] * c1);
      }
      qf[dc] = t;
    }
  }

  const char* kpt = (const char*)kfr + (size_t)bh * 262144 + p * 4096 + (size_t)lane * 16;
  const char* vpt = (const char*)vfr + (size_t)bh * 262144 + p * 4096 + (size_t)lane * 16;
  const unsigned long long* mrow = mpk + (size_t)bb * 65536 + q0 + g * 32 + col;

  f32x16 acc0, acc1;
#pragma unroll
  for (int i = 0; i < 16; ++i) { acc0[i] = 0.f; acc1[i] = 0.f; }
  float l_run = 0.f;  // partial over own (p,hh) keys only; merged in epilogue

  bf16x8 kf0 = *(const bf16x8*)(kpt + 0);
  bf16x8 kf1 = *(const bf16x8*)(kpt + 1024);
  bf16x8 kf2 = *(const bf16x8*)(kpt + 2048);
  bf16x8 kf3 = *(const bf16x8*)(kpt + 3072);
  unsigned long long bits = mrow[0];

  for (int it = 0; it < 32; ++it) {
    const int itn = (it < 31) ? it + 1 : 31;  // clamped; value unused last iter
    const char* kn = kpt + (size_t)itn * 8192;
    bf16x8 kn0 = *(const bf16x8*)(kn + 0);
    bf16x8 kn1 = *(const bf16x8*)(kn + 1024);
    bf16x8 kn2 = *(const bf16x8*)(kn + 2048);
    bf16x8 kn3 = *(const bf16x8*)(kn + 3072);
    const char* vg = vpt + (size_t)it * 8192;
    bf16x8 vf0 = *(const bf16x8*)(vg + 0);     // kc0, d 0-31
    bf16x8 vf1 = *(const bf16x8*)(vg + 1024);  // kc0, d 32-63
    bf16x8 vf2 = *(const bf16x8*)(vg + 2048);  // kc1, d 0-31
    bf16x8 vf3 = *(const bf16x8*)(vg + 3072);  // kc1, d 32-63
    const unsigned long long bits_n = mrow[(size_t)itn * 2048];

    // Bias-init masking: element r starts at 0.0 (visible) or -16384.0
    // (masked). nk = ~kb32 computed once; per element: sbfe + and (2 ops).
    const unsigned kb32 = ((unsigned)(bits >> (32 * p))) >> (4 * hh);
    const unsigned nk   = ~kb32;
    f32x16 st0;
#pragma unroll
    for (int r = 0; r < 16; ++r) {
      const int c = (r & 3) + 8 * (r >> 2);
      st0[r] = __uint_as_float((unsigned)bit_smear(nk, c) & 0xC6800000u);
    }

    // S^T = K_half * Q^T (32 keys x 32 q), K-dim 64 via 4 chained MFMAs.
    st0 = MFMA32(kf0, qf[0], st0);
    st0 = MFMA32(kf1, qf[1], st0);
    st0 = MFMA32(kf2, qf[2], st0);
    st0 = MFMA32(kf3, qf[3], st0);

    // p = exp2(s): visible scores identical to R0 (init 0.0); masked scores
    // <= -16000 underflow to exact 0 — no post-exp mask op needed.
    float Sl = 0.f;
#pragma unroll
    for (int r = 0; r < 16; ++r) {
      const float p0 = __builtin_amdgcn_exp2f(st0[r]);
      st0[r] = p0;
      Sl += p0;
    }
    l_run += Sl;

    // O^T += V' * P: B-operand is P in NATURAL lane order (V' permuted to
    // match at prepass) — no cross-lane exchange.
#pragma unroll
    for (int kc = 0; kc < 2; ++kc) {
      union { unsigned u[4]; bf16x8 v; } bbv;
      bbv.u[0] = pk_trunc(st0[8 * kc + 0], st0[8 * kc + 1]);
      bbv.u[1] = pk_trunc(st0[8 * kc + 2], st0[8 * kc + 3]);
      bbv.u[2] = pk_trunc(st0[8 * kc + 4], st0[8 * kc + 5]);
      bbv.u[3] = pk_trunc(st0[8 * kc + 6], st0[8 * kc + 7]);
      if (kc == 0) {
        acc0 = MFMA32(vf0, bbv.v, acc0);
        acc1 = MFMA32(vf1, bbv.v, acc1);
      } else {
        acc0 = MFMA32(vf2, bbv.v, acc0);
        acc1 = MFMA32(vf3, bbv.v, acc1);
      }
    }

    kf0 = kn0; kf1 = kn1; kf2 = kn2; kf3 = kn3;
    bits = bits_n;
  }

  // Merge l partials over (p,hh) and key-half O partials; normalize; store.
  lsum[g][p][hh][col] = l_run;
  __syncthreads();
  const float scale = 1.f / (lsum[g][0][0][col] + lsum[g][0][1][col] +
                             lsum[g][1][0][col] + lsum[g][1][1][col]);

#pragma unroll
  for (int dt = 0; dt < 2; ++dt)
#pragma unroll
    for (int g2 = 0; g2 < 4; ++g2) {
      f32x4 w;
#pragma unroll
      for (int j = 0; j < 4; ++j)
        w[j] = (dt ? acc1[g2 * 4 + j] : acc0[g2 * 4 + j]) * scale;
      *(f32x4*)&Oe[p][g * 32 + col][g2 * 8 + hh * 4 + dt * 32] = w;
    }
  __syncthreads();
#pragma unroll
  for (int i = 0; i < 4; ++i) {
    const int idx = tid + i * 256;
    const int row = idx >> 4, c4 = idx & 15;
    f32x4 v0 = *(const f32x4*)&Oe[0][row][c4 * 4];
    f32x4 v1 = *(const f32x4*)&Oe[1][row][c4 * 4];
    f32x4 vs = v0 + v1;
    *(f32x4*)&outp[(size_t)(bh * L + q0 + row) * D + c4 * 4] = vs;
  }
}

// ---------------- fallback (no workspace): proven R2/R3 kernel ----------------
__global__ __launch_bounds__(256, 4) void nrev_attn_fb(
    const float* __restrict__ qp, const float* __restrict__ kp,
    const float* __restrict__ vp, const int* __restrict__ maskp,
    float* __restrict__ outp) {
  constexpr int L = 2048, D = 64;
  __shared__ union alignas(16) SMem {
    struct {
      bf16_t K[64 * 72];
      bf16_t V[64 * 72];
      unsigned long long mb[64];
    } s;
    float Oe[2][64][68];
  } sm;
  __shared__ float mlbuf[2][2][32][2];

  const int tid  = threadIdx.x;
  const int lane = tid & 63;
  const int wv   = tid >> 6;
  const int p    = wv >> 1;
  const int g    = wv & 1;
  const int col  = lane & 31;
  const int hh   = lane >> 5;
  const int blk  = blockIdx.x;
  const int bh   = (blk & 7) * 4 + (blk >> 8);
  const int qt   = (blk >> 3) & 31;
  const int bb   = bh >> 4;
  const int q0   = qt * 64;
  const float c1 = 0.18033688011112042f;

  bf16x8 qf[4];
  {
    const float* gq = qp + (size_t)(bh * L + q0 + g * 32 + col) * D;
#pragma unroll
    for (int dc = 0; dc < 4; ++dc) {
      const float* ptr = gq + dc * 16 + hh * 8;
      f32x4 f0 = *(const f32x4*)ptr;
      f32x4 f1 = *(const f32x4*)(ptr + 4);
      bf16x8 t;
#pragma unroll
      for (int j = 0; j < 4; ++j) {
        t[j]     = (bf16_t)(f0[j] * c1);
        t[4 + j] = (bf16_t)(f1[j] * c1);
      }
      qf[dc] = t;
    }
  }

  f32x16 acc0, acc1;
#pragma unroll
  for (int i = 0; i < 16; ++i) { acc0[i] = 0.f; acc1[i] = 0.f; }
  float m_run = -__builtin_inff();
  float l_run = 0.f;

  for (int kt = 0; kt < L; kt += 64) {
    __syncthreads();
    {
      const int key = tid >> 2, dp = tid & 3;
      const float* gk = kp + (size_t)(bh * L + kt + key) * D + dp * 16;
      f32x4 a0 = *(const f32x4*)gk;
      f32x4 a1 = *(const f32x4*)(gk + 4);
      f32x4 a2 = *(const f32x4*)(gk + 8);
      f32x4 a3 = *(const f32x4*)(gk + 12);
      bf16x8 w0, w1;
#pragma unroll
      for (int j = 0; j < 4; ++j) {
        w0[j] = (bf16_t)a0[j]; w0[4 + j] = (bf16_t)a1[j];
        w1[j] = (bf16_t)a2[j]; w1[4 + j] = (bf16_t)a3[j];
      }
      *(bf16x8*)&sm.s.K[key * 72 + dp * 16]     = w0;
      *(bf16x8*)&sm.s.K[key * 72 + dp * 16 + 8] = w1;
    }
    {
      const int w16 = wv * 16;
      const float* gv = vp + (size_t)(bh * L + kt + w16) * D + lane;
      bf16x8 w0, w1;
#pragma unroll
      for (int i = 0; i < 8; ++i) {
        w0[i] = (bf16_t)fminf(gv[(size_t)i * D], 0.f);
        w1[i] = (bf16_t)fminf(gv[(size_t)(i + 8) * D], 0.f);
      }
      *(bf16x8*)&sm.s.V[lane * 72 + w16]     = w0;
      *(bf16x8*)&sm.s.V[lane * 72 + w16 + 8] = w1;
    }
    for (int i = 0; i < 16; ++i) {
      const int row = wv * 16 + i;
      int mv = maskp[(size_t)bb * L * L + (size_t)(q0 + row) * L + kt + lane];
      unsigned long long bal = __ballot(mv != 0);
      if (lane == 0) sm.s.mb[row] = bal;
    }
    __syncthreads();

    f32x16 st0;
#pragma unroll
    for (int i = 0; i < 16; ++i) st0[i] = 0.f;
#pragma unroll
    for (int dc = 0; dc < 4; ++dc) {
      bf16x8 a0 = *(const bf16x8*)&sm.s.K[(p * 32 + col) * 72 + dc * 16 + hh * 8];
      st0 = MFMA32(a0, qf[dc], st0);
    }

    float M = st0[0];
#pragma unroll
    for (int r = 1; r < 16; ++r) M = fmaxf(M, st0[r]);
#pragma unroll
    for (int sh = 1; sh < 64; sh <<= 1) M = fmaxf(M, __shfl_xor(M, sh));
    if (M > m_run) {
      const float alpha = exp2f(m_run - M);
      l_run *= alpha;
#pragma unroll
      for (int r = 0; r < 16; ++r) { acc0[r] *= alpha; acc1[r] *= alpha; }
      m_run = M;
    }

    const unsigned long long bits = sm.s.mb[g * 32 + col];
    const unsigned kb = ((unsigned)(bits >> (32 * p))) >> (4 * hh);
    float Sl = 0.f;
#pragma unroll
    for (int r = 0; r < 16; ++r) {
      const int c = (r & 3) + 8 * (r >> 2);
      float p0 = exp2f(st0[r] - m_run);
      p0 = ((kb >> c) & 1u) ? p0 : 0.f;
      st0[r] = p0;
      Sl += p0;
    }
    Sl += __shfl_xor(Sl, 32);
    l_run += Sl;

#pragma unroll
    for (int kc = 0; kc < 2; ++kc) {
      const unsigned pk0  = pk_bf16(st0[8 * kc + 0], st0[8 * kc + 1]);
      const unsigned pk0b = pk_bf16(st0[8 * kc + 2], st0[8 * kc + 3]);
      const unsigned pk1  = pk_bf16(st0[8 * kc + 4], st0[8 * kc + 5]);
      const unsigned pk1b = pk_bf16(st0[8 * kc + 6], st0[8 * kc + 7]);
      const unsigned sh0  = __shfl_xor(pk0, 32);
      const unsigned sh0b = __shfl_xor(pk0b, 32);
      const unsigned sh1  = __shfl_xor(pk1, 32);
      const unsigned sh1b = __shfl_xor(pk1b, 32);
      union { unsigned u[4]; bf16x8 v; } bbv;
      bbv.u[0] = hh ? sh1  : pk0;
      bbv.u[1] = hh ? sh1b : pk0b;
      bbv.u[2] = hh ? pk1  : sh0;
      bbv.u[3] = hh ? pk1b : sh0b;
      const int kbase = p * 32 + kc * 16 + hh * 8;
      bf16x8 av0 = *(const bf16x8*)&sm.s.V[col * 72        + kbase];
      bf16x8 av1 = *(const bf16x8*)&sm.s.V[(col + 32) * 72 + kbase];
      acc0 = MFMA32(av0, bbv.v, acc0);
      acc1 = MFMA32(av1, bbv.v, acc1);
    }
  }

  if (hh == 0) {
    mlbuf[g][p][col][0] = m_run;
    mlbuf[g][p][col][1] = l_run;
  }
  __syncthreads();
  const float m0 = mlbuf[g][0][col][0], l0v = mlbuf[g][0][col][1];
  const float m1 = mlbuf[g][1][col][0], l1v = mlbuf[g][1][col][1];
  const float ms = fmaxf(m0, m1);
  const float a0s = exp2f(m0 - ms), a1s = exp2f(m1 - ms);
  const float lst = a0s * l0v + a1s * l1v;
  const float scale = (p ? a1s : a0s) / lst;

#pragma unroll
  for (int dt = 0; dt < 2; ++dt)
#pragma unroll
    for (int g2 = 0; g2 < 4; ++g2) {
      f32x4 w;
#pragma unroll
      for (int j = 0; j < 4; ++j)
        w[j] = (dt ? acc1[g2 * 4 + j] : acc0[g2 * 4 + j]) * scale;
      *(f32x4*)&sm.Oe[p][g * 32 + col][g2 * 8 + hh * 4 + dt * 32] = w;
    }
  __syncthreads();
#pragma unroll
  for (int i = 0; i < 4; ++i) {
    const int idx = tid + i * 256;
    const int row = idx >> 4, c4 = idx & 15;
    f32x4 v0 = *(const f32x4*)&sm.Oe[0][row][c4 * 4];
    f32x4 v1 = *(const f32x4*)&sm.Oe[1][row][c4 * 4];
    f32x4 vs = v0 + v1;
    *(f32x4*)&outp[(size_t)(bh * L + q0 + row) * D + c4 * 4] = vs;
  }
}

extern "C" void kernel_launch(void* const* d_in, const int* in_sizes, int n_in,
                              void* d_out, int out_size, void* d_ws, size_t ws_size,
                              hipStream_t stream) {
  (void)in_sizes; (void)n_in; (void)out_size;
  const float* qp = (const float*)d_in[0];
  const float* kp = (const float*)d_in[1];
  const float* vp = (const float*)d_in[2];
  const int*   mp = (const int*)d_in[3];
  float* op = (float*)d_out;

  // ws layout: K' frag bf16 8 MiB | V' frag bf16 8 MiB | mask words 1 MiB
  const size_t kOff = 0;
  const size_t vOff = (size_t)8 * 1024 * 1024;
  const size_t mOff = (size_t)16 * 1024 * 1024;
  const size_t need = mOff + (size_t)1024 * 1024;

  if (d_ws != nullptr && ws_size >= need) {
    bf16_t* kb = (bf16_t*)((char*)d_ws + kOff);
    bf16_t* vt = (bf16_t*)((char*)d_ws + vOff);
    unsigned long long* mpk = (unsigned long long*)((char*)d_ws + mOff);
    hipLaunchKernelGGL(prepass, dim3(6144), dim3(256), 0, stream,
                       kp, vp, mp, kb, vt, mpk);
    hipLaunchKernelGGL(nrev_attn_ws, dim3(1024), dim3(256), 0, stream,
                       qp, kb, vt, mpk, op);
  } else {
    hipLaunchKernelGGL(nrev_attn_fb, dim3(1024), dim3(256), 0, stream,
                       qp, kp, vp, mp, op);
  }
}